// Round 10
// baseline (399.506 us; speedup 1.0000x reference)
//
#include <hip/hip_runtime.h>
#include <stdint.h>

typedef float f32x4 __attribute__((ext_vector_type(4)));
typedef short s16x8 __attribute__((ext_vector_type(8)));
typedef unsigned u32x4 __attribute__((ext_vector_type(4)));

#define B_SZ 256
#define A_RG 196
#define DVD  2048
#define RNN  1024
#define H_SZ 512
#define M_TOT (B_SZ * A_RG)   // 50176 flat rows
#define BM 128
#define BK 32
#define NKT (DVD / BK)        // 64 K-tiles
#define NBLK (M_TOT / BM)     // 392

__device__ __forceinline__ unsigned short f2bf(float f) {
    unsigned u = __builtin_bit_cast(unsigned, f);
    u = u + 0x7FFFu + ((u >> 16) & 1u);   // RNE
    return (unsigned short)(u >> 16);
}

__device__ __forceinline__ unsigned cvt2(float a, float b) {
    unsigned r;
    asm("v_cvt_pk_bf16_f32 %0, %1, %2" : "=v"(r) : "v"(a), "v"(b));
    return r;
}

__device__ __forceinline__ void gll16(const void* g, void* l) {
    __builtin_amdgcn_global_load_lds(
        (const __attribute__((address_space(1))) void*)g,
        (__attribute__((address_space(3))) void*)l, 16, 0, 0);
}

// ---------------------------------------------------------------------------
// Kernel 1: W_v [2048,512] fp32 -> Wt6 bf16, laid out so a LINEAR gll copy of
// one K-tile (32KB) lands in the swizzled LDS layout the B-frag reads expect:
// idx = (k>>5)*16384 + col*32 + (((k>>3)&3)^(col&3))*8 + (k&7)   [ushorts]
// ---------------------------------------------------------------------------
__global__ __launch_bounds__(256) void k_prepW(const float* __restrict__ Wv,
                                               unsigned short* __restrict__ Wt6) {
    __shared__ float tile[64][65];
    int kb = blockIdx.x >> 3, ct = blockIdx.x & 7;
    int k0 = kb * 64, c0 = ct * 64;
    int t = threadIdx.x;
    int cl = t & 63, rq = t >> 6;
#pragma unroll
    for (int i = 0; i < 16; ++i) {
        int r = rq * 16 + i;
        tile[r][cl] = Wv[(size_t)(k0 + r) * H_SZ + c0 + cl];
    }
    __syncthreads();
    int kl = t & 63;
#pragma unroll
    for (int i = 0; i < 16; ++i) {
        int cr = rq * 16 + i;
        int col = c0 + cr;
        int k = k0 + kl;
        int slot = ((k >> 3) & 3) ^ (col & 3);
        size_t dst = (size_t)(k >> 5) * (H_SZ * BK)
                   + (size_t)col * 32 + slot * 8 + (k & 7);
        Wt6[dst] = f2bf(tile[kl][cr]);
    }
}

// ---------------------------------------------------------------------------
// Kernel 2: base[b,h] = h_att[b]@W_ha + prev_h2[b]@W_hv + b_ha + b_hv + b_v
// ---------------------------------------------------------------------------
__global__ __launch_bounds__(256) void k_base(const float* __restrict__ h_att,
                                              const float* __restrict__ prev_h2,
                                              const float* __restrict__ W_ha,
                                              const float* __restrict__ b_ha,
                                              const float* __restrict__ W_hv,
                                              const float* __restrict__ b_hv,
                                              const float* __restrict__ b_v,
                                              float* __restrict__ base_g) {
    __shared__ float ha_s[4][RNN];
    __shared__ float pv_s[4][RNN];
    int bg = blockIdx.x >> 2, hg = blockIdx.x & 3;
    int t = threadIdx.x;
#pragma unroll
    for (int i = 0; i < 16; ++i) {
        int idx = i * 256 + t;
        int bl = idx >> 10, k = idx & 1023;
        ha_s[bl][k] = h_att[(size_t)(bg * 4 + bl) * RNN + k];
        pv_s[bl][k] = prev_h2[(size_t)(bg * 4 + bl) * RNN + k];
    }
    __syncthreads();
    int h = hg * 128 + (t & 127);
    int br = t >> 7;
    float aA0 = 0, aA1 = 0, aV0 = 0, aV1 = 0;
#pragma unroll 4
    for (int k = 0; k < RNN; ++k) {
        float w1 = W_ha[(size_t)k * H_SZ + h];
        float w2 = W_hv[(size_t)k * H_SZ + h];
        aA0 = fmaf(ha_s[br * 2][k],     w1, aA0);
        aA1 = fmaf(ha_s[br * 2 + 1][k], w1, aA1);
        aV0 = fmaf(pv_s[br * 2][k],     w2, aV0);
        aV1 = fmaf(pv_s[br * 2 + 1][k], w2, aV1);
    }
    float bias = b_ha[h] + b_hv[h] + b_v[h];
    base_g[(size_t)(bg * 4 + br * 2) * H_SZ + h]     = aA0 + aV0 + bias;
    base_g[(size_t)(bg * 4 + br * 2 + 1) * H_SZ + h] = aA1 + aV1 + bias;
}

// ---------------------------------------------------------------------------
// Kernel 3: phase-template GEMM [50176,2048]x[2048,512] + fused score reduce.
// BM=128, BN=512(full), BK=32; 512 thr = 8 waves (2M x 4N, wave 64x128,
// acc[4][8]=128). Per K-tile 2 phases, each {stage-issue + ds_reads} ->
// barrier -> lgkmcnt(0) -> setprio -> 16 MFMA -> setprio -> barrier.
// B via gll (linear copy of pre-swizzled Wt6, dbuf); A reg-staged fp32->bf16
// (loads 2 tiles ahead = 4 phases > HBM latency), granule-XOR swizzled.
// vmcnt(2) once per tile, never 0 mid-loop. LDS 82KB, 1 block/CU.
// ---------------------------------------------------------------------------
__global__ __launch_bounds__(512, 2) void k_gemm(const float* __restrict__ imgs,
                                                 const unsigned short* __restrict__ Wt6,
                                                 const float* __restrict__ base_g,
                                                 const float* __restrict__ W_f,
                                                 float* __restrict__ att_g) {
    __shared__ __align__(16) short A_s[2][BM * BK];    // 2 x 8 KB
    __shared__ __align__(16) short B_s[2][H_SZ * BK];  // 2 x 32 KB
    __shared__ float att_part[4][BM];

    const int m0 = blockIdx.x * BM;
    const int t = threadIdx.x;
    const int lane = t & 63, w = t >> 6;
    const int wm = w >> 2, wn = w & 3;
    const int lr = lane & 15, g = lane >> 4;

    // ---- A global source: thread t -> row t>>2, floats (t&3)*8 .. +7 ----
    const float* Ag = imgs + (size_t)(m0 + (t >> 2)) * DVD + (t & 3) * 8;
    // A ds_write: row t>>2, granule (t&3) ^ (row&3)
    const unsigned awr = (unsigned)((t >> 2) * 64 + ((((t & 3) ^ ((t >> 2) & 3))) << 4));

    // ---- fragment read addresses (granule-XOR swizzle, 64B rows) ----
    unsigned ard[4], brd[8];
#pragma unroll
    for (int mf = 0; mf < 4; ++mf) {
        int r = wm * 64 + mf * 16 + lr;
        ard[mf] = (unsigned)(r * 64 + ((g ^ (r & 3)) << 4));
    }
#pragma unroll
    for (int n = 0; n < 8; ++n) {
        int c = wn * 128 + n * 16 + lr;
        brd[n] = (unsigned)(c * 64 + ((g ^ (c & 3)) << 4));
    }

    f32x4 acc[4][8] = {};
    f32x4 rE0, rE1, rO0, rO1;   // A reg double-buffer (sets E/O by tile parity)

    auto ldA = [&](int kt, f32x4& a0, f32x4& a1) {
        const f32x4* p = (const f32x4*)(Ag + (size_t)kt * BK);
        a0 = p[0]; a1 = p[1];
    };
    auto wrA = [&](int j, const f32x4& a0, const f32x4& a1) {
        u32x4 pk;
        pk[0] = cvt2(a0[0], a0[1]);
        pk[1] = cvt2(a0[2], a0[3]);
        pk[2] = cvt2(a1[0], a1[1]);
        pk[3] = cvt2(a1[2], a1[3]);
        *(s16x8*)((char*)A_s[j & 1] + awr) = __builtin_bit_cast(s16x8, pk);
    };
    auto stB = [&](int kt) {   // wave w stages contiguous 4x1KB (uniform base)
        const char* s = (const char*)Wt6 + (size_t)kt * 32768 + w * 4096 + (size_t)lane * 16;
        char* d = (char*)B_s[kt & 1] + w * 4096 + lane * 16;
#pragma unroll
        for (int i = 0; i < 4; ++i)
            gll16(s + i * 1024, d + i * 1024);
    };

#define PH_BAR_IN()                                                            \
    __builtin_amdgcn_s_barrier();                                              \
    asm volatile("s_waitcnt lgkmcnt(0)" ::: "memory");                         \
    __builtin_amdgcn_sched_barrier(0);                                         \
    __builtin_amdgcn_s_setprio(1);

#define PH_BAR_OUT()                                                           \
    __builtin_amdgcn_s_setprio(0);                                             \
    __builtin_amdgcn_s_barrier();

    // TILE: phase0 {stB(kt+1); read af[4],bq[0..3]; MFMA n0-3}
    //       phase1 {ldA(kt+2)->SL; wrA(kt+1)<-SW; read bq[4..7]; MFMA n4-7; vmcnt(2)}
#define TILE(KT_, SL0, SL1, SW0, SW1)                                          \
    {                                                                          \
        const char* Ac = (const char*)A_s[(KT_) & 1];                          \
        const char* Bc = (const char*)B_s[(KT_) & 1];                          \
        stB((KT_) + 1);                                                        \
        s16x8 af[4], bq[4];                                                    \
        _Pragma("unroll")                                                      \
        for (int mf = 0; mf < 4; ++mf) af[mf] = *(const s16x8*)(Ac + ard[mf]); \
        _Pragma("unroll")                                                      \
        for (int n = 0; n < 4; ++n) bq[n] = *(const s16x8*)(Bc + brd[n]);      \
        PH_BAR_IN();                                                           \
        _Pragma("unroll")                                                      \
        for (int mf = 0; mf < 4; ++mf)                                         \
            _Pragma("unroll")                                                  \
            for (int n = 0; n < 4; ++n)                                        \
                acc[mf][n] = __builtin_amdgcn_mfma_f32_16x16x32_bf16(          \
                    af[mf], bq[n], acc[mf][n], 0, 0, 0);                       \
        PH_BAR_OUT();                                                          \
        ldA((KT_) + 2, SL0, SL1);                                              \
        wrA((KT_) + 1, SW0, SW1);                                              \
        _Pragma("unroll")                                                      \
        for (int n = 0; n < 4; ++n) bq[n] = *(const s16x8*)(Bc + brd[4 + n]);  \
        PH_BAR_IN();                                                           \
        _Pragma("unroll")                                                      \
        for (int mf = 0; mf < 4; ++mf)                                         \
            _Pragma("unroll")                                                  \
            for (int n = 0; n < 4; ++n)                                        \
                acc[mf][4 + n] = __builtin_amdgcn_mfma_f32_16x16x32_bf16(      \
                    af[mf], bq[n], acc[mf][4 + n], 0, 0, 0);                   \
        __builtin_amdgcn_s_setprio(0);                                         \
        asm volatile("s_waitcnt vmcnt(2)" ::: "memory");                       \
        __builtin_amdgcn_sched_barrier(0);                                     \
        __builtin_amdgcn_s_barrier();                                          \
    }

    // ---- prologue: A(0)->E, A(1)->O, B(0) staged; write A(0); drain ----
    ldA(0, rE0, rE1);
    ldA(1, rO0, rO1);
    stB(0);
    wrA(0, rE0, rE1);
    asm volatile("s_waitcnt vmcnt(0) lgkmcnt(0)" ::: "memory");
    __builtin_amdgcn_sched_barrier(0);
    __builtin_amdgcn_s_barrier();

    // ---- main: tiles 0..61 (even: load->E write-from O; odd: mirrored) ----
    for (int kt = 0; kt < NKT - 2; kt += 2) {
        TILE(kt,     rE0, rE1, rO0, rO1);
        TILE(kt + 1, rO0, rO1, rE0, rE1);
    }
    // ---- tail tile 62: stage B(63), write A(63) (from O), drain vmem ----
    {
        const char* Ac = (const char*)A_s[0];
        const char* Bc = (const char*)B_s[0];
        stB(NKT - 1);
        s16x8 af[4], bq[4];
#pragma unroll
        for (int mf = 0; mf < 4; ++mf) af[mf] = *(const s16x8*)(Ac + ard[mf]);
#pragma unroll
        for (int n = 0; n < 4; ++n) bq[n] = *(const s16x8*)(Bc + brd[n]);
        PH_BAR_IN();
#pragma unroll
        for (int mf = 0; mf < 4; ++mf)
#pragma unroll
            for (int n = 0; n < 4; ++n)
                acc[mf][n] = __builtin_amdgcn_mfma_f32_16x16x32_bf16(
                    af[mf], bq[n], acc[mf][n], 0, 0, 0);
        PH_BAR_OUT();
        wrA(NKT - 1, rO0, rO1);
#pragma unroll
        for (int n = 0; n < 4; ++n) bq[n] = *(const s16x8*)(Bc + brd[4 + n]);
        PH_BAR_IN();
#pragma unroll
        for (int mf = 0; mf < 4; ++mf)
#pragma unroll
            for (int n = 0; n < 4; ++n)
                acc[mf][4 + n] = __builtin_amdgcn_mfma_f32_16x16x32_bf16(
                    af[mf], bq[n], acc[mf][4 + n], 0, 0, 0);
        __builtin_amdgcn_s_setprio(0);
        asm volatile("s_waitcnt vmcnt(0)" ::: "memory");
        __builtin_amdgcn_sched_barrier(0);
        __builtin_amdgcn_s_barrier();
    }
    // ---- tail tile 63: compute only ----
    {
        const char* Ac = (const char*)A_s[1];
        const char* Bc = (const char*)B_s[1];
        s16x8 af[4], bq[4];
#pragma unroll
        for (int mf = 0; mf < 4; ++mf) af[mf] = *(const s16x8*)(Ac + ard[mf]);
#pragma unroll
        for (int n = 0; n < 4; ++n) bq[n] = *(const s16x8*)(Bc + brd[n]);
        PH_BAR_IN();
#pragma unroll
        for (int mf = 0; mf < 4; ++mf)
#pragma unroll
            for (int n = 0; n < 4; ++n)
                acc[mf][n] = __builtin_amdgcn_mfma_f32_16x16x32_bf16(
                    af[mf], bq[n], acc[mf][n], 0, 0, 0);
        PH_BAR_OUT();
#pragma unroll
        for (int n = 0; n < 4; ++n) bq[n] = *(const s16x8*)(Bc + brd[4 + n]);
        asm volatile("s_waitcnt lgkmcnt(0)" ::: "memory");
        __builtin_amdgcn_sched_barrier(0);
#pragma unroll
        for (int mf = 0; mf < 4; ++mf)
#pragma unroll
            for (int n = 0; n < 4; ++n)
                acc[mf][4 + n] = __builtin_amdgcn_mfma_f32_16x16x32_bf16(
                    af[mf], bq[n], acc[mf][4 + n], 0, 0, 0);
    }
#undef TILE
#undef PH_BAR_IN
#undef PH_BAR_OUT

    // ---- epilogue: att[row] = sum_h relu(p + base[b(row),h]) * W_f[h] ----
    const int b0 = m0 / A_RG;
    const int b1 = min(b0 + 1, B_SZ - 1);
    float wfv[8], bs0[8], bs1[8];
#pragma unroll
    for (int n = 0; n < 8; ++n) {
        int col = wn * 128 + n * 16 + lr;
        wfv[n] = W_f[col];
        bs0[n] = base_g[(size_t)b0 * H_SZ + col];
        bs1[n] = base_g[(size_t)b1 * H_SZ + col];
    }
#pragma unroll
    for (int m = 0; m < 4; ++m) {
        float pj[4] = {0.f, 0.f, 0.f, 0.f};
#pragma unroll
        for (int j = 0; j < 4; ++j) {
            int row = wm * 64 + m * 16 + g * 4 + j;
            bool second = (m0 + row) >= (b0 + 1) * A_RG;
#pragma unroll
            for (int n = 0; n < 8; ++n) {
                float bsv = second ? bs1[n] : bs0[n];
                pj[j] += fmaxf(acc[m][n][j] + bsv, 0.f) * wfv[n];
            }
        }
#pragma unroll
        for (int j = 0; j < 4; ++j) {
            float s = pj[j];
            s += __shfl_xor(s, 1);
            s += __shfl_xor(s, 2);
            s += __shfl_xor(s, 4);
            s += __shfl_xor(s, 8);     // sum over the 16 lr-lanes of this row
            if (lr == 0) {
                int row = wm * 64 + m * 16 + g * 4 + j;
                att_part[wn][row] = s;  // unique writer per (wn,row)
            }
        }
    }
    __syncthreads();

    if (t < BM) {
        att_g[m0 + t] = att_part[0][t] + att_part[1][t] +
                        att_part[2][t] + att_part[3][t];
    }
}

// ---------------------------------------------------------------------------
// Kernel 4: softmax over A=196 + weighted sum. grid (2 d-halves, 256 b),
// block 256; thread t owns one f32x4 col group (1KB/wave), 4 rotating accs.
// ---------------------------------------------------------------------------
__global__ __launch_bounds__(256) void k_ws(const float* __restrict__ imgs,
                                            const float* __restrict__ att_g,
                                            float* __restrict__ out) {
    __shared__ float alpha_s[A_RG];
    int b = blockIdx.y, dc = blockIdx.x;
    int t = threadIdx.x;

    if (t < 64) {
        float v[4], e[4];
        float mx = -1e30f;
#pragma unroll
        for (int i = 0; i < 4; ++i) {
            int r = i * 64 + t;
            v[i] = (r < A_RG) ? att_g[(size_t)b * A_RG + r] : -1e30f;
            mx = fmaxf(mx, v[i]);
        }
        for (int d = 1; d < 64; d <<= 1) mx = fmaxf(mx, __shfl_xor(mx, d));
        float sum = 0.f;
#pragma unroll
        for (int i = 0; i < 4; ++i) {
            int r = i * 64 + t;
            e[i] = (r < A_RG) ? __expf(v[i] - mx) : 0.f;
            sum += e[i];
        }
        for (int d = 1; d < 64; d <<= 1) sum += __shfl_xor(sum, d);
        float inv = 1.0f / sum;
#pragma unroll
        for (int i = 0; i < 4; ++i) {
            int r = i * 64 + t;
            if (r < A_RG) alpha_s[r] = e[i] * inv;
        }
    }
    __syncthreads();

    const float* ib = imgs + (size_t)b * A_RG * DVD + dc * 1024 + t * 4;
    f32x4 o0 = {}, o1 = {}, o2 = {}, o3 = {};
    for (int a = 0; a < A_RG; a += 4) {           // 196 = 49*4 exact
        float al0 = alpha_s[a],     al1 = alpha_s[a + 1];
        float al2 = alpha_s[a + 2], al3 = alpha_s[a + 3];
        f32x4 v0 = *(const f32x4*)(ib + (size_t)(a)     * DVD);
        f32x4 v1 = *(const f32x4*)(ib + (size_t)(a + 1) * DVD);
        f32x4 v2 = *(const f32x4*)(ib + (size_t)(a + 2) * DVD);
        f32x4 v3 = *(const f32x4*)(ib + (size_t)(a + 3) * DVD);
#pragma unroll
        for (int j = 0; j < 4; ++j) {
            o0[j] = fmaf(al0, v0[j], o0[j]);
            o1[j] = fmaf(al1, v1[j], o1[j]);
            o2[j] = fmaf(al2, v2[j], o2[j]);
            o3[j] = fmaf(al3, v3[j], o3[j]);
        }
    }
    f32x4 o;
#pragma unroll
    for (int j = 0; j < 4; ++j) o[j] = (o0[j] + o1[j]) + (o2[j] + o3[j]);
    *(f32x4*)(out + (size_t)b * DVD + dc * 1024 + t * 4) = o;
}

// ---------------------------------------------------------------------------
extern "C" void kernel_launch(void* const* d_in, const int* in_sizes, int n_in,
                              void* d_out, int out_size, void* d_ws, size_t ws_size,
                              hipStream_t stream) {
    const float* h_att   = (const float*)d_in[0];
    const float* prev_h2 = (const float*)d_in[1];
    const float* imgs    = (const float*)d_in[2];
    const float* W_v     = (const float*)d_in[3];
    const float* b_v     = (const float*)d_in[4];
    const float* W_ha    = (const float*)d_in[5];
    const float* b_ha    = (const float*)d_in[6];
    const float* W_hv    = (const float*)d_in[7];
    const float* b_hv    = (const float*)d_in[8];
    const float* W_f     = (const float*)d_in[9];
    // d_in[10] = b_f: softmax-invariant additive constant -> unused

    // ws layout: [0,2MB) Wt6 bf16 (k-tile-major, granule-swizzled);
    //            [2MB,+512KB) base fp32 [256][512]; then att fp32 [50176]
    unsigned short* Wt6 = (unsigned short*)d_ws;
    float* base_g = (float*)((char*)d_ws + (size_t)DVD * H_SZ * 2);
    float* att_g  = (float*)((char*)d_ws + (size_t)DVD * H_SZ * 2 + (size_t)B_SZ * H_SZ * 4);
    float* out = (float*)d_out;

    hipLaunchKernelGGL(k_prepW, dim3(256), dim3(256), 0, stream, W_v, Wt6);
    hipLaunchKernelGGL(k_base, dim3(256), dim3(256), 0, stream,
                       h_att, prev_h2, W_ha, b_ha, W_hv, b_hv, b_v, base_g);
    hipLaunchKernelGGL(k_gemm, dim3(NBLK), dim3(512), 0, stream,
                       imgs, Wt6, base_g, W_f, att_g);
    hipLaunchKernelGGL(k_ws, dim3(2, B_SZ), dim3(256), 0, stream,
                       imgs, att_g, out);
}